// Round 11
// baseline (1074.872 us; speedup 1.0000x reference)
//
#include <hip/hip_runtime.h>
#include <math.h>

#define SDIM 1000
#define KPAD 1024
#define HDIM 200
#define MDIM 100
#define NPAD 208
#define TSTEPS 1024
#define BATCH 128
#define MT (BATCH*TSTEPS)
#define TOTX ((size_t)MT*(size_t)SDIM)

// ws layout: [0, 425984) WpT bf16 [208][1024]; [458752, +52428800) Z bf16 [131072][200]
#define Z_OFF 458752

typedef _Float16 half2_t __attribute__((ext_vector_type(2)));
typedef __attribute__((ext_vector_type(8))) short short8;
typedef __attribute__((ext_vector_type(4))) float f32x4;

static __device__ __forceinline__ unsigned short f2bf(float f) {
    unsigned u = __float_as_uint(f);
    unsigned r = 0x7fffu + ((u >> 16) & 1u);   // RNE
    return (unsigned short)((u + r) >> 16);
}
static __device__ __forceinline__ float bf2f(unsigned short h) {
    return __uint_as_float((unsigned)h << 16);
}
static __device__ __forceinline__ half2_t as_h2(unsigned v) {
    union { unsigned u; half2_t h; } c; c.u = v; return c.h;
}
static __device__ __forceinline__ unsigned as_u32(half2_t h) {
    union { half2_t h; unsigned u; } c; c.h = h; return c.u;
}
static __device__ __forceinline__ half2_t pk2(float a, float b) {
    half2_t r; r[0] = (_Float16)a; r[1] = (_Float16)b; return r;
}

// Raw workgroup barrier: drains ONLY lgkm (LDS); global ops stay in flight.
static __device__ __forceinline__ void wg_barrier() {
    asm volatile("s_waitcnt lgkmcnt(0)" ::: "memory");
    __builtin_amdgcn_s_barrier();
    asm volatile("" ::: "memory");
}

// ---------------------------------------------------------------------------
// Kernel 0: WpT[n][k] = relu(w_s[k]) * W1[k][n]  (bf16, transposed, padded)
// ---------------------------------------------------------------------------
__global__ __launch_bounds__(256) void prep_wpt(const float* __restrict__ w_s,
                                                const float* __restrict__ W1,
                                                unsigned short* __restrict__ wpt) {
    int idx = blockIdx.x * 256 + threadIdx.x;   // 208*1024 total
    int n = idx >> 10, k = idx & (KPAD - 1);
    float v = 0.f;
    if (n < HDIM && k < SDIM) {
        float ws = fmaxf(w_s[k], 0.f);
        v = ws * W1[k * HDIM + n];
    }
    wpt[idx] = f2bf(v);
}

// ---------------------------------------------------------------------------
// Kernel 1: Z = bf16(X) @ WpT^T.  BM=128 (4 waves x 2 m-tiles), BN=208, BK=32.
// A and B staged in LDS (double-buffered).  (unchanged)
// ---------------------------------------------------------------------------
__global__ __launch_bounds__(256) void gemm_z(const float* __restrict__ X,
                                              const unsigned short* __restrict__ wpt,
                                              unsigned short* __restrict__ Z) {
    __shared__ __align__(16) unsigned short Abuf[2][128][40];
    __shared__ __align__(16) unsigned short Bbuf[2][13][16][40];
    const int t = threadIdx.x;
    const int m0 = blockIdx.x * 128;
    const int lane = t & 63, w = t >> 6;

    f32x4 acc[2][13];
#pragma unroll
    for (int mt = 0; mt < 2; ++mt)
#pragma unroll
        for (int i = 0; i < 13; ++i) acc[mt][i] = (f32x4){0.f, 0.f, 0.f, 0.f};

    auto stageA = [&](int bsel, int k0) {
        const int row = t >> 1, half = t & 1;
        size_t g = (size_t)(m0 + row) * SDIM + (size_t)(k0 + half * 16);
        float4 f0{}, f1{}, f2{}, f3{};
        if (g + 15 < TOTX) {
            f0 = *(const float4*)(X + g);      f1 = *(const float4*)(X + g + 4);
            f2 = *(const float4*)(X + g + 8);  f3 = *(const float4*)(X + g + 12);
        }
        short8 p0, p1;
        p0[0]=(short)f2bf(f0.x); p0[1]=(short)f2bf(f0.y); p0[2]=(short)f2bf(f0.z); p0[3]=(short)f2bf(f0.w);
        p0[4]=(short)f2bf(f1.x); p0[5]=(short)f2bf(f1.y); p0[6]=(short)f2bf(f1.z); p0[7]=(short)f2bf(f1.w);
        p1[0]=(short)f2bf(f2.x); p1[1]=(short)f2bf(f2.y); p1[2]=(short)f2bf(f2.z); p1[3]=(short)f2bf(f2.w);
        p1[4]=(short)f2bf(f3.x); p1[5]=(short)f2bf(f3.y); p1[6]=(short)f2bf(f3.z); p1[7]=(short)f2bf(f3.w);
        *(short8*)&Abuf[bsel][row][half * 16]     = p0;
        *(short8*)&Abuf[bsel][row][half * 16 + 8] = p1;
    };
    auto stageB = [&](int bsel, int k0) {
#pragma unroll
        for (int j = 0; j < 4; ++j) {
            int e = t + 256 * j;
            if (e < 832) {
                int n = e >> 2, q = e & 3;
                short8 v = *(const short8*)(wpt + (size_t)n * KPAD + k0 + q * 8);
                *(short8*)&Bbuf[bsel][n >> 4][n & 15][q * 8] = v;
            }
        }
    };

    stageA(0, 0);
    stageB(0, 0);
#pragma unroll 1
    for (int it = 0; it < 32; ++it) {
        __syncthreads();
        if (it + 1 < 32) { stageA((it + 1) & 1, (it + 1) * 32); stageB((it + 1) & 1, (it + 1) * 32); }
        const int bsel = it & 1;
        const short8 av0 = *(const short8*)&Abuf[bsel][w * 32 + (lane & 15)][(lane >> 4) * 8];
        const short8 av1 = *(const short8*)&Abuf[bsel][w * 32 + 16 + (lane & 15)][(lane >> 4) * 8];
#pragma unroll
        for (int nt = 0; nt < 13; ++nt) {
            const short8 bv = *(const short8*)&Bbuf[bsel][nt][lane & 15][(lane >> 4) * 8];
            acc[0][nt] = __builtin_amdgcn_mfma_f32_16x16x32_bf16(av0, bv, acc[0][nt], 0, 0, 0);
            acc[1][nt] = __builtin_amdgcn_mfma_f32_16x16x32_bf16(av1, bv, acc[1][nt], 0, 0, 0);
        }
    }

    const int colb = lane & 15;
#pragma unroll
    for (int mt = 0; mt < 2; ++mt) {
        const int rowb = m0 + w * 32 + mt * 16 + (lane >> 4) * 4;
#pragma unroll
        for (int nt = 0; nt < 13; ++nt) {
            int col = nt * 16 + colb;
            if (col < HDIM) {
#pragma unroll
                for (int r = 0; r < 4; ++r)
                    Z[(size_t)(rowb + r) * HDIM + col] = f2bf(acc[mt][nt][r]);
            }
        }
    }
}

// ---------------------------------------------------------------------------
// Kernel 2: sequential scan, 1 WG (2 waves, 128 thr) per batch element.
//  wave w lane l<50 owns: h-cols n0=100w+2l, n1=n0+1; m-cols j0=2l, j1=2l+1.
//  mm1: both cols full-K (kappa folded into W1 regs); m broadcast = 50
//       in-wave readlanes of mpk (plain m, fp16 pairs).
//  h pack: in-lane pk2(hA,hB) -- NO shfl.
//  mm2: k-split by wave = wave's OWN h -> 50 in-wave readlanes of hpk.
//  cross-wave: one ds_write_b64 (partials) + 1 barrier + one b64x2 read.
//  y: wave1 lanes 50-59 ride the mm1 dot block with Wy weights (plain m).
// ---------------------------------------------------------------------------
#define KEXP 1.9235933878519513f   /* (4/3)*log2(e): e^{2x} = 2^{(s+b2)*KEXP} */
#define KS   0.81873075307798182f  /* exp(-1/5) */

__global__ __launch_bounds__(128, 1) void scan_seq(const unsigned short* __restrict__ Z,
        const float* __restrict__ W1, const float* __restrict__ b1,
        const float* __restrict__ W2, const float* __restrict__ b2,
        const float* __restrict__ Wy, const float* __restrict__ by,
        float* __restrict__ out) {
    __shared__ __align__(16) float part[2][2][104];   // [buf][wave][col]
    __shared__ float kap_s[104];

    const int t = threadIdx.x;
    const int b = blockIdx.x;
    const int w = t >> 6, lane = t & 63;
    const bool hAct = lane < 50;
    const bool yAct = (w == 1) && (lane >= 50 && lane < 60);
    const int o = lane - 50;
    const int n0 = 100 * w + 2 * lane, n1 = n0 + 1;   // h cols (hAct)
    const int j0 = 2 * lane, j1 = j0 + 1;             // m cols (hAct)

    if (t < 104) {
        float kv = 0.f;
        if (t < MDIM) {                     // kappa_m in fp64 to match numpy
            double lg = 1.0000000434294482
                      + (double)t * ((2.9999999995657055 - 1.0000000434294482) / 99.0);
            double tau = exp(lg * 2.302585092994046);
            kv = (float)exp(-1.0 / tau);
        }
        kap_s[t] = kv;
    }
    __syncthreads();

    // mm1 weights (kappa-folded) for 2 cols; y lanes get plain Wy in slot A
    half2_t w1A[50], w1B[50], w2A[50], w2B[50];
#pragma unroll
    for (int c = 0; c < 50; ++c) {
        float a0 = 0.f, a1 = 0.f, b0 = 0.f, b1v = 0.f;
        float p0 = 0.f, p1 = 0.f, q0 = 0.f, q1 = 0.f;
        if (hAct) {
            a0 = kap_s[2*c]   * W1[(SDIM + 2*c)     * HDIM + n0];
            a1 = kap_s[2*c+1] * W1[(SDIM + 2*c + 1) * HDIM + n0];
            b0 = kap_s[2*c]   * W1[(SDIM + 2*c)     * HDIM + n1];
            b1v= kap_s[2*c+1] * W1[(SDIM + 2*c + 1) * HDIM + n1];
            int k0 = 100 * w + 2 * c, k1 = k0 + 1;
            p0 = W2[k0 * MDIM + j0]; p1 = W2[k1 * MDIM + j0];
            q0 = W2[k0 * MDIM + j1]; q1 = W2[k1 * MDIM + j1];
        } else if (yAct) {
            a0 = Wy[(2*c) * 10 + o];
            a1 = Wy[(2*c + 1) * 10 + o];
        }
        w1A[c] = pk2(a0, a1);
        w1B[c] = pk2(b0, b1v);
        w2A[c] = pk2(p0, p1);
        w2B[c] = pk2(q0, q1);
    }
    float bA = hAct ? b1[n0] : (yAct ? by[o] : 0.f);
    float bB = hAct ? b1[n1] : 0.f;

    float kap0 = 0.f, kap1 = 0.f, cm0 = 0.f, cm1 = 0.f, b2k0 = 0.f, b2k1 = 0.f;
    if (hAct) {
        kap0 = kap_s[j0]; kap1 = kap_s[j1];
        cm0 = 3.f * (1.f - kap0); cm1 = 3.f * (1.f - kap1);
        b2k0 = b2[j0] * KEXP; b2k1 = b2[j1] * KEXP;
    }

    const unsigned short* Zb = Z + (size_t)b * TSTEPS * HDIM;
    float* outb = out + (size_t)b * TSTEPS * 10;

    float uA = 0.f, uB = 0.f, m0 = 0.f, m1 = 0.f;
    unsigned mpk = 0;
    unsigned zr0 = 0, zr1 = 0, zr2 = 0, zr3 = 0;   // depth-4 z prefetch (dword = 2 bf16)
    if (hAct) {
        zr0 = *(const unsigned*)(Zb + (size_t)0 * HDIM + n0);
        zr1 = *(const unsigned*)(Zb + (size_t)1 * HDIM + n0);
        zr2 = *(const unsigned*)(Zb + (size_t)2 * HDIM + n0);
        zr3 = *(const unsigned*)(Zb + (size_t)3 * HDIM + n0);
    }
    __syncthreads();

    auto stepf = [&](const int P, unsigned& zreg, const int st) {
        // ---- u update + z prefetch (4 ahead)
        float zA = __uint_as_float(zreg << 16);
        float zB = __uint_as_float(zreg & 0xffff0000u);
        uA = KS * uA + zA;
        uB = KS * uB + zB;
        if (hAct) {
            int stn = st + 4; stn = (stn < TSTEPS) ? stn : TSTEPS - 1;
            zreg = *(const unsigned*)(Zb + (size_t)stn * HDIM + n0);
        }

        // ---- m broadcast: 50 in-wave readlanes of mpk (plain m, fp16 pairs)
        int sm_[50];
#pragma unroll
        for (int c = 0; c < 50; ++c) sm_[c] = __builtin_amdgcn_readlane((int)mpk, c);

        // ---- mm1: 2 cols, 8 chains (y lanes ride col A with Wy)
        float a0 = bA + uA, a1 = 0.f, a2 = 0.f, a3 = 0.f;
        float c0 = bB + uB, c1 = 0.f, c2 = 0.f, c3 = 0.f;
#pragma unroll
        for (int c = 0; c < 48; c += 4) {
            a0 = __builtin_amdgcn_fdot2(w1A[c+0], as_h2((unsigned)sm_[c+0]), a0, false);
            c0 = __builtin_amdgcn_fdot2(w1B[c+0], as_h2((unsigned)sm_[c+0]), c0, false);
            a1 = __builtin_amdgcn_fdot2(w1A[c+1], as_h2((unsigned)sm_[c+1]), a1, false);
            c1 = __builtin_amdgcn_fdot2(w1B[c+1], as_h2((unsigned)sm_[c+1]), c1, false);
            a2 = __builtin_amdgcn_fdot2(w1A[c+2], as_h2((unsigned)sm_[c+2]), a2, false);
            c2 = __builtin_amdgcn_fdot2(w1B[c+2], as_h2((unsigned)sm_[c+2]), c2, false);
            a3 = __builtin_amdgcn_fdot2(w1A[c+3], as_h2((unsigned)sm_[c+3]), a3, false);
            c3 = __builtin_amdgcn_fdot2(w1B[c+3], as_h2((unsigned)sm_[c+3]), c3, false);
        }
        a0 = __builtin_amdgcn_fdot2(w1A[48], as_h2((unsigned)sm_[48]), a0, false);
        c0 = __builtin_amdgcn_fdot2(w1B[48], as_h2((unsigned)sm_[48]), c0, false);
        a1 = __builtin_amdgcn_fdot2(w1A[49], as_h2((unsigned)sm_[49]), a1, false);
        c1 = __builtin_amdgcn_fdot2(w1B[49], as_h2((unsigned)sm_[49]), c1, false);
        float rA = (a0 + a1) + (a2 + a3);
        float rB = (c0 + c1) + (c2 + c3);
        if (yAct && st > 0) outb[(size_t)(st - 1) * 10 + o] = rA;   // y_{st-1}

        // ---- h pack in-lane (no shfl) + 50 in-wave readlanes
        unsigned hpk = as_u32(pk2(fmaxf(rA, 0.f), fmaxf(rB, 0.f)));
        int sh_[50];
#pragma unroll
        for (int c = 0; c < 50; ++c) sh_[c] = __builtin_amdgcn_readlane((int)hpk, c);

        // ---- mm2 partial: 2 cols over this wave's own 100 h's, 4 chains
        float e00 = 0.f, e01 = 0.f, e10 = 0.f, e11 = 0.f;
#pragma unroll
        for (int c = 0; c < 50; c += 2) {
            e00 = __builtin_amdgcn_fdot2(w2A[c],   as_h2((unsigned)sh_[c]),   e00, false);
            e10 = __builtin_amdgcn_fdot2(w2B[c],   as_h2((unsigned)sh_[c]),   e10, false);
            e01 = __builtin_amdgcn_fdot2(w2A[c+1], as_h2((unsigned)sh_[c+1]), e01, false);
            e11 = __builtin_amdgcn_fdot2(w2B[c+1], as_h2((unsigned)sh_[c+1]), e11, false);
        }
        if (hAct)
            *(float2*)&part[P][w][j0] = make_float2(e00 + e01, e10 + e11);
        wg_barrier();

        // ---- combine 2 partials, tanh (exp2+rcp), m update
        if (hAct) {
            float2 p0 = *(const float2*)&part[P][0][j0];
            float2 p1 = *(const float2*)&part[P][1][j0];
            float s0 = p0.x + p1.x;
            float s1 = p0.y + p1.y;
            float E0 = __builtin_amdgcn_exp2f(fmaf(s0, KEXP, b2k0));
            float E1 = __builtin_amdgcn_exp2f(fmaf(s1, KEXP, b2k1));
            float dm0 = 1.7159f - 3.4318f * __builtin_amdgcn_rcpf(E0 + 1.f);
            float dm1 = 1.7159f - 3.4318f * __builtin_amdgcn_rcpf(E1 + 1.f);
            m0 = fmaf(kap0, m0, cm0 * dm0);   // m_t = kap*m_{t-1} + 3(1-kap)*dm
            m1 = fmaf(kap1, m1, cm1 * dm1);
        }
        mpk = as_u32(pk2(m0, m1));
    };

#pragma unroll 1
    for (int st = 0; st < TSTEPS; st += 4) {
        stepf(0, zr0, st);
        stepf(1, zr1, st + 1);
        stepf(0, zr2, st + 2);
        stepf(1, zr3, st + 3);
    }

    // final y (step TSTEPS-1) from the last m broadcast
    {
        int sm_[50];
#pragma unroll
        for (int c = 0; c < 50; ++c) sm_[c] = __builtin_amdgcn_readlane((int)mpk, c);
        if (yAct) {
            float d0 = bA, d1 = 0.f, d2 = 0.f, d3 = 0.f;
#pragma unroll
            for (int c = 0; c < 48; c += 4) {
                d0 = __builtin_amdgcn_fdot2(w1A[c+0], as_h2((unsigned)sm_[c+0]), d0, false);
                d1 = __builtin_amdgcn_fdot2(w1A[c+1], as_h2((unsigned)sm_[c+1]), d1, false);
                d2 = __builtin_amdgcn_fdot2(w1A[c+2], as_h2((unsigned)sm_[c+2]), d2, false);
                d3 = __builtin_amdgcn_fdot2(w1A[c+3], as_h2((unsigned)sm_[c+3]), d3, false);
            }
            d0 = __builtin_amdgcn_fdot2(w1A[48], as_h2((unsigned)sm_[48]), d0, false);
            d1 = __builtin_amdgcn_fdot2(w1A[49], as_h2((unsigned)sm_[49]), d1, false);
            outb[(size_t)(TSTEPS - 1) * 10 + o] = (d0 + d1) + (d2 + d3);
        }
    }
}

extern "C" void kernel_launch(void* const* d_in, const int* in_sizes, int n_in,
                              void* d_out, int out_size, void* d_ws, size_t ws_size,
                              hipStream_t stream) {
    const float* X  = (const float*)d_in[0];
    const float* ws = (const float*)d_in[1];
    const float* W1 = (const float*)d_in[2];
    const float* b1 = (const float*)d_in[3];
    const float* W2 = (const float*)d_in[4];
    const float* b2 = (const float*)d_in[5];
    const float* Wy = (const float*)d_in[6];
    const float* by = (const float*)d_in[7];
    float* out = (float*)d_out;

    unsigned short* wpt = (unsigned short*)d_ws;
    unsigned short* Z   = (unsigned short*)((char*)d_ws + Z_OFF);

    hipLaunchKernelGGL(prep_wpt, dim3((NPAD * KPAD) / 256), dim3(256), 0, stream, ws, W1, wpt);
    hipLaunchKernelGGL(gemm_z, dim3(MT / 128), dim3(256), 0, stream, X, wpt, Z);
    hipLaunchKernelGGL(scan_seq, dim3(BATCH), dim3(128), 0, stream,
                       Z, W1, b1, W2, b2, Wy, by, out);
}